// Round 1
// baseline (5113.470 us; speedup 1.0000x reference)
//
#include <hip/hip_runtime.h>
#include <math.h>

// FermiNet-like forward, N=1024, DIM=3, all fp32.
//
// Restructuring vs reference:
//  * h2 (n,n,C) is NEVER materialized: the output depends on h2 only through
//    its column means at 4 stages. One fused pair kernel (k2_pairs) carries
//    each pair through feat(49) -> tanh L0 -> L1 -> L2 in registers and
//    block-reduces per-column sums (rbar + 3x32 stage sums).
//  * Pairwise trig factorizes over particles: cos(2pik(xi-xj)) = ci*cj+si*sj,
//    sin(2pik(xi-xj)) = si*cj-ci*sj, sin(pi(xi-xj)) = spi*cpj-cpi*spj.
//    Per-particle tables (54 floats each) computed once in k1_tables.
//  * Feature means (g2 used at layer 0) are closed-form from per-particle
//    sums: mean_i cos(2pik(xi-xj)) = cj*Cbar + sj*Sbar. Only rbar needs the
//    pair loop.
//  * h1 path is tiny (1024x160x64 per layer): 4 small kernels with atomic
//    row-mean accumulation between layers (mean(h1) is a sequential dep).
//
// Workspace layout (floats); total 285936 floats ~= 1.15 MB.

#define NP 1024

// ---- workspace offsets (in floats) ----
static const size_t OF_TCK  = 0;                  // 24*1024  cos(2pi k x_d)
static const size_t OF_TSK  = OF_TCK + 24*NP;     // 24*1024  sin(2pi k x_d)
static const size_t OF_TCP  = OF_TSK + 24*NP;     // 3*1024   cos(pi x_d)
static const size_t OF_TSP  = OF_TCP + 3*NP;      // 3*1024   sin(pi x_d)
static const size_t OF_CSUM = OF_TSP + 3*NP;      // 24  sum_i cos
static const size_t OF_SSUM = OF_CSUM + 24;       // 24  sum_i sin
static const size_t OF_HSUM = OF_SSUM + 24;       // 3*64  h1 row-sum per layer
static const size_t OF_RACC = OF_HSUM + 192;      // 1024  sum_i r(i,j)
static const size_t OF_M0   = OF_RACC + NP;       // 1024*32 sum_i h2 stage0
static const size_t OF_M1   = OF_M0 + NP*32;      // 1024*32 stage1
static const size_t OF_M2   = OF_M1 + NP*32;      // 1024*32 stage2
static const size_t OF_H1A  = OF_M2 + NP*32;      // 1024*64
static const size_t OF_H1B  = OF_H1A + NP*64;     // 1024*64
// end: OF_H1B + NP*64 = 285936 floats

__device__ __forceinline__ float ftanh(float x) {
    // tanh(x) = 1 - 2/(exp(2x)+1); exact at +-inf, ~1e-7 abs err.
    float e = __expf(2.0f * x);
    return 1.0f - __fdividef(2.0f, e + 1.0f);
}

// ---------------------------------------------------------------------------
// K1: per-particle trig tables + column sums + zero HSUM.  <<<1, 1024>>>
// ---------------------------------------------------------------------------
__global__ __launch_bounds__(1024) void k1_tables(
    const float* __restrict__ X,
    float* __restrict__ TCK, float* __restrict__ TSK,
    float* __restrict__ TCP, float* __restrict__ TSP,
    float* __restrict__ CSUM, float* __restrict__ SSUM,
    float* __restrict__ HSUM)
{
    const int i = threadIdx.x;
    float ck[24], sk[24];
#pragma unroll
    for (int d = 0; d < 3; ++d) {
        float x = X[i*3 + d];
        float sp, cp;
        sincospif(x, &sp, &cp);                  // sin(pi x), cos(pi x)
        TSP[d*NP + i] = sp;
        TCP[d*NP + i] = cp;
#pragma unroll
        for (int k = 0; k < 8; ++k) {
            float s, c;
            sincospif(2.0f*(float)(k+1)*x, &s, &c);   // sin/cos(2pi(k+1)x)
            ck[k*3 + d] = c;  sk[k*3 + d] = s;
            TCK[(k*3 + d)*NP + i] = c;
            TSK[(k*3 + d)*NP + i] = s;
        }
    }
    __shared__ float part[48*16];
    const int lane = i & 63, wv = i >> 6;
#pragma unroll
    for (int v = 0; v < 24; ++v) {
        float a = ck[v], b = sk[v];
#pragma unroll
        for (int off = 32; off; off >>= 1) {
            a += __shfl_down(a, off, 64);
            b += __shfl_down(b, off, 64);
        }
        if (lane == 0) { part[v*16 + wv] = a; part[(24+v)*16 + wv] = b; }
    }
    __syncthreads();
    if (i < 48) {
        float s = 0.f;
#pragma unroll
        for (int w = 0; w < 16; ++w) s += part[i*16 + w];
        if (i < 24) CSUM[i] = s; else SSUM[i-24] = s;
    }
    if (i < 192) HSUM[i] = 0.0f;   // ws is poisoned each launch; zero atomics dst
}

// ---------------------------------------------------------------------------
// K2: the heavy pair kernel. One block per column j; 256 threads x 4 i-steps.
// Accumulates sum_i over {r, h2_stage0, h2_stage1, h2_stage2}.
// ---------------------------------------------------------------------------
__global__ __launch_bounds__(256, 2) void k2_pairs(
    const float* __restrict__ W20, const float* __restrict__ b20,
    const float* __restrict__ W21, const float* __restrict__ b21,
    const float* __restrict__ W22, const float* __restrict__ b22,
    const float* __restrict__ TCK, const float* __restrict__ TSK,
    const float* __restrict__ TCP, const float* __restrict__ TSP,
    float* __restrict__ RACC, float* __restrict__ M0,
    float* __restrict__ M1, float* __restrict__ M2)
{
    __shared__ __align__(16) float sW0[49*32];
    __shared__ __align__(16) float sW1[32*32];
    __shared__ __align__(16) float sW2[32*32];
    __shared__ float sB[96];
    __shared__ float sJ[54];
    __shared__ float sPart[97*4];

    const int tid = threadIdx.x;
    const int j = blockIdx.x;

    for (int v = tid; v < 49*32; v += 256) sW0[v] = W20[v];
    for (int v = tid; v < 32*32; v += 256) sW1[v] = W21[v];
    for (int v = tid; v < 32*32; v += 256) sW2[v] = W22[v];
    if (tid < 32) { sB[tid] = b20[tid]; sB[32+tid] = b21[tid]; sB[64+tid] = b22[tid]; }
    if (tid < 24) { sJ[tid] = TCK[tid*NP + j]; sJ[24+tid] = TSK[tid*NP + j]; }
    if (tid < 3)  { sJ[48+tid] = TCP[tid*NP + j]; sJ[51+tid] = TSP[tid*NP + j]; }
    __syncthreads();

    float a0[32], a1[32], a2[32];
#pragma unroll
    for (int c = 0; c < 32; ++c) { a0[c] = 0.f; a1[c] = 0.f; a2[c] = 0.f; }
    float racc = 0.f;

#pragma unroll 1
    for (int it = 0; it < 4; ++it) {
        const int i = it*256 + tid;
        float z[32];
#pragma unroll
        for (int c = 0; c < 32; ++c) z[c] = sB[c];

        // r feature: norm of sin(pi*(xi-xj)); exactly 0 at i==j.
        float r2 = 0.f;
#pragma unroll
        for (int d = 0; d < 3; ++d) {
            float spi = TSP[d*NP + i], cpi = TCP[d*NP + i];
            float sd = fmaf(spi, sJ[48+d], -(cpi * sJ[51+d]));
            r2 = fmaf(sd, sd, r2);
        }
        float r = sqrtf(r2);
        racc += r;
        {
            const float4* w = (const float4*)sW0;   // row 0 of W2_0
#pragma unroll
            for (int q = 0; q < 8; ++q) {
                float4 wv = w[q];
                z[q*4+0] = fmaf(r, wv.x, z[q*4+0]);
                z[q*4+1] = fmaf(r, wv.y, z[q*4+1]);
                z[q*4+2] = fmaf(r, wv.z, z[q*4+2]);
                z[q*4+3] = fmaf(r, wv.w, z[q*4+3]);
            }
        }
        // cos/sin features, k-major then (cos d0..d2, sin d0..d2)
#pragma unroll
        for (int kd = 0; kd < 24; ++kd) {
            float cki = TCK[kd*NP + i], ski = TSK[kd*NP + i];
            float ckj = sJ[kd], skj = sJ[24+kd];
            float cc = fmaf(cki, ckj, ski * skj);          // cos(2pik rij)
            float ss = fmaf(ski, ckj, -(cki * skj));       // sin(2pik rij)
            const int k = kd / 3, d = kd - k*3;
            const float4* wc  = (const float4*)(sW0 + (1 + k*6 + d)*32);
            const float4* wsn = (const float4*)(sW0 + (4 + k*6 + d)*32);
#pragma unroll
            for (int q = 0; q < 8; ++q) {
                float4 wa = wc[q], wb = wsn[q];
                z[q*4+0] = fmaf(cc, wa.x, fmaf(ss, wb.x, z[q*4+0]));
                z[q*4+1] = fmaf(cc, wa.y, fmaf(ss, wb.y, z[q*4+1]));
                z[q*4+2] = fmaf(cc, wa.z, fmaf(ss, wb.z, z[q*4+2]));
                z[q*4+3] = fmaf(cc, wa.w, fmaf(ss, wb.w, z[q*4+3]));
            }
        }
        float h0[32];
#pragma unroll
        for (int c = 0; c < 32; ++c) { float h = ftanh(z[c]); h0[c] = h; a0[c] += h; z[c] = sB[32+c]; }
#pragma unroll
        for (int k = 0; k < 32; ++k) {
            float hv = h0[k];
            const float4* wr = (const float4*)(sW1 + k*32);
#pragma unroll
            for (int q = 0; q < 8; ++q) {
                float4 wv = wr[q];
                z[q*4+0] = fmaf(hv, wv.x, z[q*4+0]);
                z[q*4+1] = fmaf(hv, wv.y, z[q*4+1]);
                z[q*4+2] = fmaf(hv, wv.z, z[q*4+2]);
                z[q*4+3] = fmaf(hv, wv.w, z[q*4+3]);
            }
        }
        float h1v[32];
#pragma unroll
        for (int c = 0; c < 32; ++c) { float h = ftanh(z[c]) + h0[c]; h1v[c] = h; a1[c] += h; z[c] = sB[64+c]; }
#pragma unroll
        for (int k = 0; k < 32; ++k) {
            float hv = h1v[k];
            const float4* wr = (const float4*)(sW2 + k*32);
#pragma unroll
            for (int q = 0; q < 8; ++q) {
                float4 wv = wr[q];
                z[q*4+0] = fmaf(hv, wv.x, z[q*4+0]);
                z[q*4+1] = fmaf(hv, wv.y, z[q*4+1]);
                z[q*4+2] = fmaf(hv, wv.z, z[q*4+2]);
                z[q*4+3] = fmaf(hv, wv.w, z[q*4+3]);
            }
        }
#pragma unroll
        for (int c = 0; c < 32; ++c) { a2[c] += ftanh(z[c]) + h1v[c]; }
    }

    // block reduce 97 values (4 waves) -> LDS partials -> global
    const int lane = tid & 63, wid = tid >> 6;
#define RED1(val, idx) { float v_ = (val); \
    v_ += __shfl_down(v_, 32, 64); v_ += __shfl_down(v_, 16, 64); \
    v_ += __shfl_down(v_, 8, 64);  v_ += __shfl_down(v_, 4, 64);  \
    v_ += __shfl_down(v_, 2, 64);  v_ += __shfl_down(v_, 1, 64);  \
    if (lane == 0) sPart[(idx)*4 + wid] = v_; }
    RED1(racc, 0);
#pragma unroll
    for (int c = 0; c < 32; ++c) RED1(a0[c], 1 + c);
#pragma unroll
    for (int c = 0; c < 32; ++c) RED1(a1[c], 33 + c);
#pragma unroll
    for (int c = 0; c < 32; ++c) RED1(a2[c], 65 + c);
#undef RED1
    __syncthreads();
    if (tid < 97) {
        float s = sPart[tid*4+0] + sPart[tid*4+1] + sPart[tid*4+2] + sPart[tid*4+3];
        if (tid == 0)      RACC[j] = s;
        else if (tid < 33) M0[j*32 + (tid-1)]  = s;
        else if (tid < 65) M1[j*32 + (tid-33)] = s;
        else               M2[j*32 + (tid-65)] = s;
    }
}

// ---------------------------------------------------------------------------
// Phase B: h1 path. Thread = (row j, 8-channel chunk q). 8192 threads.
// ---------------------------------------------------------------------------
#define FMA8(fv, wptr) do { \
    const float4* w4_ = (const float4*)(wptr); \
    float4 a_ = w4_[0], b_ = w4_[1]; \
    z[0]=fmaf((fv),a_.x,z[0]); z[1]=fmaf((fv),a_.y,z[1]); \
    z[2]=fmaf((fv),a_.z,z[2]); z[3]=fmaf((fv),a_.w,z[3]); \
    z[4]=fmaf((fv),b_.x,z[4]); z[5]=fmaf((fv),b_.y,z[5]); \
    z[6]=fmaf((fv),b_.z,z[6]); z[7]=fmaf((fv),b_.w,z[7]); \
} while (0)

__global__ __launch_bounds__(256) void l0_kernel(
    const float* __restrict__ Tsc, const float* __restrict__ W10,
    const float* __restrict__ b10,
    const float* __restrict__ TCK, const float* __restrict__ TSK,
    const float* __restrict__ CSUM, const float* __restrict__ SSUM,
    const float* __restrict__ RACC,
    float* __restrict__ H1A, float* __restrict__ HSUM0)
{
    const int gid = blockIdx.x*256 + threadIdx.x;
    const int j = gid >> 3, q = gid & 7, c0 = q*8;
    const float inv_n = 1.0f/1024.0f;
    const float t = Tsc[0];

    float z[8];
#pragma unroll
    for (int u = 0; u < 8; ++u) z[u] = b10[c0+u];

    // f rows 0..16 = h1_init feats, rows 17..33 = g1 (identical rows -> same)
    FMA8(t, W10 + 0*64 + c0);
    FMA8(t, W10 + 17*64 + c0);
#pragma unroll
    for (int k = 0; k < 8; ++k) {
        float s, c; sincospif(2.0f*(float)(k+1)*t, &s, &c);
        FMA8(c, W10 + (1+2*k)*64 + c0);
        FMA8(c, W10 + (18+2*k)*64 + c0);
        FMA8(s, W10 + (2+2*k)*64 + c0);
        FMA8(s, W10 + (19+2*k)*64 + c0);
    }
    // row 34: rbar
    {
        float rb = RACC[j] * inv_n;
        FMA8(rb, W10 + 34*64 + c0);
    }
    // rows 35..82: analytic feature means
#pragma unroll
    for (int kd = 0; kd < 24; ++kd) {
        float cj = TCK[kd*NP + j], sj = TSK[kd*NP + j];
        float Cb = CSUM[kd]*inv_n, Sb = SSUM[kd]*inv_n;
        float cm = fmaf(cj, Cb, sj*Sb);          // mean_i cos(2pik(xi-xj))
        float sm = fmaf(Sb, cj, -(Cb*sj));       // mean_i sin(2pik(xi-xj))
        int k = kd/3, d = kd - k*3;
        FMA8(cm, W10 + (35 + k*6 + d)*64 + c0);
        FMA8(sm, W10 + (38 + k*6 + d)*64 + c0);
    }
#pragma unroll
    for (int u = 0; u < 8; ++u) {
        float h = ftanh(z[u]);                   // layer 0: no residual
        H1A[j*64 + c0 + u] = h;
        atomicAdd(&HSUM0[c0+u], h);
    }
}

template<int LAYER>
__global__ __launch_bounds__(256) void lx_kernel(
    const float* __restrict__ W, const float* __restrict__ b,
    const float* __restrict__ hin, float* __restrict__ hout,
    const float* __restrict__ HSin, float* __restrict__ HSout,
    const float* __restrict__ M,
    const float* __restrict__ Wf, const float* __restrict__ X,
    float* __restrict__ out)
{
    const int tid = threadIdx.x;
    const int gid = blockIdx.x*256 + tid;
    const int j = gid >> 3, q = gid & 7, c0 = q*8;
    const float inv_n = 1.0f/1024.0f;

    float z[8];
#pragma unroll
    for (int u = 0; u < 8; ++u) z[u] = b[c0+u];
    const float* hrow = hin + j*64;
#pragma unroll 4
    for (int p = 0; p < 64; ++p) {
        float fv = hrow[p];
        FMA8(fv, W + p*64 + c0);
    }
#pragma unroll 4
    for (int p = 0; p < 64; ++p) {
        float fv = HSin[p] * inv_n;
        FMA8(fv, W + (64+p)*64 + c0);
    }
    const float* mrow = M + j*32;
#pragma unroll 4
    for (int p = 0; p < 32; ++p) {
        float fv = mrow[p] * inv_n;
        FMA8(fv, W + (128+p)*64 + c0);
    }
    float h[8];
#pragma unroll
    for (int u = 0; u < 8; ++u) h[u] = ftanh(z[u]) + hrow[c0+u];  // residual

    if (LAYER < 3) {
#pragma unroll
        for (int u = 0; u < 8; ++u) {
            hout[j*64 + c0 + u] = h[u];
            atomicAdd(&HSout[c0+u], h[u]);
        }
    } else {
        __shared__ float red[256][3];
        float p0 = 0.f, p1 = 0.f, p2 = 0.f;
#pragma unroll
        for (int u = 0; u < 8; ++u) {
            float hv = h[u];
            const float* wf = Wf + (c0+u)*3;
            p0 = fmaf(hv, wf[0], p0);
            p1 = fmaf(hv, wf[1], p1);
            p2 = fmaf(hv, wf[2], p2);
        }
        red[tid][0] = p0; red[tid][1] = p1; red[tid][2] = p2;
        __syncthreads();
        if (q == 0) {
            float s0 = 0.f, s1 = 0.f, s2 = 0.f;
#pragma unroll
            for (int qq = 0; qq < 8; ++qq) {
                s0 += red[tid+qq][0]; s1 += red[tid+qq][1]; s2 += red[tid+qq][2];
            }
#pragma unroll
            for (int d = 0; d < 3; ++d) {
                float fx = 2.0f * X[j*3 + d];
                fx = fminf(fmaxf(fx, -10.0f), 10.0f);        // clip(2x,-10,10)
                float s = (d == 0 ? s0 : (d == 1 ? s1 : s2));
                out[j*3 + d] = -s * fx;
            }
        }
    }
}

// ---------------------------------------------------------------------------
extern "C" void kernel_launch(void* const* d_in, const int* in_sizes, int n_in,
                              void* d_out, int out_size, void* d_ws, size_t ws_size,
                              hipStream_t stream)
{
    const float* X   = (const float*)d_in[0];
    const float* Tsc = (const float*)d_in[1];
    const float* W10 = (const float*)d_in[2];  const float* b10 = (const float*)d_in[3];
    const float* W11 = (const float*)d_in[4];  const float* b11 = (const float*)d_in[5];
    const float* W12 = (const float*)d_in[6];  const float* b12 = (const float*)d_in[7];
    const float* W13 = (const float*)d_in[8];  const float* b13 = (const float*)d_in[9];
    const float* W20 = (const float*)d_in[10]; const float* b20 = (const float*)d_in[11];
    const float* W21 = (const float*)d_in[12]; const float* b21 = (const float*)d_in[13];
    const float* W22 = (const float*)d_in[14]; const float* b22 = (const float*)d_in[15];
    const float* Wf  = (const float*)d_in[16];

    float* ws  = (float*)d_ws;       // needs >= 285936 floats (~1.15 MB)
    float* out = (float*)d_out;

    float* TCK = ws + OF_TCK;  float* TSK = ws + OF_TSK;
    float* TCP = ws + OF_TCP;  float* TSP = ws + OF_TSP;
    float* CSUM = ws + OF_CSUM; float* SSUM = ws + OF_SSUM;
    float* HSUM = ws + OF_HSUM; float* RACC = ws + OF_RACC;
    float* M0 = ws + OF_M0; float* M1 = ws + OF_M1; float* M2 = ws + OF_M2;
    float* H1A = ws + OF_H1A; float* H1B = ws + OF_H1B;

    k1_tables<<<1, 1024, 0, stream>>>(X, TCK, TSK, TCP, TSP, CSUM, SSUM, HSUM);
    k2_pairs<<<NP, 256, 0, stream>>>(W20, b20, W21, b21, W22, b22,
                                     TCK, TSK, TCP, TSP, RACC, M0, M1, M2);
    l0_kernel<<<32, 256, 0, stream>>>(Tsc, W10, b10, TCK, TSK, CSUM, SSUM, RACC,
                                      H1A, HSUM + 0*64);
    lx_kernel<1><<<32, 256, 0, stream>>>(W11, b11, H1A, H1B, HSUM + 0*64, HSUM + 1*64,
                                         M0, (const float*)nullptr, (const float*)nullptr,
                                         (float*)nullptr);
    lx_kernel<2><<<32, 256, 0, stream>>>(W12, b12, H1B, H1A, HSUM + 1*64, HSUM + 2*64,
                                         M1, (const float*)nullptr, (const float*)nullptr,
                                         (float*)nullptr);
    lx_kernel<3><<<32, 256, 0, stream>>>(W13, b13, H1A, H1B, HSUM + 2*64, (float*)nullptr,
                                         M2, Wf, X, out);
}

// Round 2
// 1420.596 us; speedup vs baseline: 3.5995x; 3.5995x over previous
//
#include <hip/hip_runtime.h>
#include <math.h>

// FermiNet-like forward, N=1024, DIM=3, all fp32.
//
// Round-1 lesson: the v0 pair kernel kept ~192 live floats/thread at
// VGPR_Count=128 -> catastrophic scratch spill (11.6 GB HBM traffic/launch,
// VALUBusy 3%). v1 restructures the pair kernel:
//   thread = (8 output channels) x (4 i-rows); 4 lanes (tid&3) cooperate on
//   each i. Per-thread state ~120-150 VGPRs -> no spill. Each LDS weight
//   float4 is reused for 4 i's (4x fewer ds_read_b128). h0/h1 exchange
//   between the 4 cooperating lanes via __shfl_xor (in-wave by construction).
//
// Math identical to v0 (which PASSED, absmax 1.9e-6):
//   h2 never materialized; pair trig factorized via per-particle tables;
//   layer-0 feature means closed-form; only rbar + 3 stage sums need pairs.

#define NP 1024

// ---- workspace offsets (in floats) ----
static const size_t OF_TCS  = 0;                   // float2[24*NP] (cos,sin) 2pi k x_d
static const size_t OF_TP2  = OF_TCS + 48*NP;      // float2[3*NP]  (cos,sin) pi x_d
static const size_t OF_CSUM = OF_TP2 + 6*NP;       // 24  sum_i cos
static const size_t OF_SSUM = OF_CSUM + 24;        // 24  sum_i sin
static const size_t OF_HSUM = OF_SSUM + 24;        // 3*64  h1 row-sum per layer
static const size_t OF_RACC = OF_HSUM + 192;       // 1024  sum_i r(i,j)
static const size_t OF_M0   = OF_RACC + NP;        // 1024*32 sum_i h2 stage0
static const size_t OF_M1   = OF_M0 + NP*32;       // 1024*32 stage1
static const size_t OF_M2   = OF_M1 + NP*32;       // 1024*32 stage2
static const size_t OF_H1A  = OF_M2 + NP*32;       // 1024*64
static const size_t OF_H1B  = OF_H1A + NP*64;      // 1024*64
// end: OF_H1B + NP*64 = 285936 floats (~1.15 MB)

__device__ __forceinline__ float ftanh(float x) {
    float e = __expf(2.0f * x);
    return 1.0f - __fdividef(2.0f, e + 1.0f);
}

// ---------------------------------------------------------------------------
// K1: per-particle trig tables (interleaved float2) + column sums + zero HSUM.
// ---------------------------------------------------------------------------
__global__ __launch_bounds__(1024) void k1_tables(
    const float* __restrict__ X,
    float2* __restrict__ TCS, float2* __restrict__ TP2,
    float* __restrict__ CSUM, float* __restrict__ SSUM,
    float* __restrict__ HSUM)
{
    const int i = threadIdx.x;
    float ck[24], sk[24];
#pragma unroll
    for (int d = 0; d < 3; ++d) {
        float x = X[i*3 + d];
        float sp, cp;
        sincospif(x, &sp, &cp);
        TP2[d*NP + i] = make_float2(cp, sp);
#pragma unroll
        for (int k = 0; k < 8; ++k) {
            float s, c;
            sincospif(2.0f*(float)(k+1)*x, &s, &c);
            ck[k*3 + d] = c;  sk[k*3 + d] = s;
            TCS[(k*3 + d)*NP + i] = make_float2(c, s);
        }
    }
    __shared__ float part[48*16];
    const int lane = i & 63, wv = i >> 6;
#pragma unroll
    for (int v = 0; v < 24; ++v) {
        float a = ck[v], b = sk[v];
#pragma unroll
        for (int off = 32; off; off >>= 1) {
            a += __shfl_down(a, off, 64);
            b += __shfl_down(b, off, 64);
        }
        if (lane == 0) { part[v*16 + wv] = a; part[(24+v)*16 + wv] = b; }
    }
    __syncthreads();
    if (i < 48) {
        float s = 0.f;
#pragma unroll
        for (int w = 0; w < 16; ++w) s += part[i*16 + w];
        if (i < 24) CSUM[i] = s; else SSUM[i-24] = s;
    }
    if (i < 192) HSUM[i] = 0.0f;
}

// ---------------------------------------------------------------------------
// K2: pair kernel. Block = column j. thread: q = tid&3 (channels q*8..q*8+7),
// g = tid>>2 (i = g + 64*m, m=0..15, processed 4 at a time).
// ---------------------------------------------------------------------------
__global__ __launch_bounds__(256, 3) void k2_pairs(
    const float* __restrict__ W20, const float* __restrict__ b20,
    const float* __restrict__ W21, const float* __restrict__ b21,
    const float* __restrict__ W22, const float* __restrict__ b22,
    const float2* __restrict__ TCS, const float2* __restrict__ TP2,
    float* __restrict__ RACC, float* __restrict__ M0,
    float* __restrict__ M1, float* __restrict__ M2)
{
    __shared__ __align__(16) float sW0[49*32];
    __shared__ __align__(16) float sW1[32*32];
    __shared__ __align__(16) float sW2[32*32];
    __shared__ float sB[96];
    __shared__ float sJ[54];      // [0..23] c_j, [24..47] s_j, [48..50] cp_j, [51..53] sp_j
    __shared__ float sPart[4][97];

    const int tid = threadIdx.x;
    const int j = blockIdx.x;
    const int q = tid & 3;
    const int g = tid >> 2;
    const int c0 = q * 8;

    for (int v = tid; v < 49*32; v += 256) sW0[v] = W20[v];
    for (int v = tid; v < 32*32; v += 256) sW1[v] = W21[v];
    for (int v = tid; v < 32*32; v += 256) sW2[v] = W22[v];
    if (tid < 32) { sB[tid] = b20[tid]; sB[32+tid] = b21[tid]; sB[64+tid] = b22[tid]; }
    if (tid < 24) { float2 cs = TCS[tid*NP + j]; sJ[tid] = cs.x; sJ[24+tid] = cs.y; }
    if (tid < 3)  { float2 pv = TP2[tid*NP + j]; sJ[48+tid] = pv.x; sJ[51+tid] = pv.y; }
    __syncthreads();

    float a0[8], a1[8], a2[8];
#pragma unroll
    for (int u = 0; u < 8; ++u) { a0[u] = 0.f; a1[u] = 0.f; a2[u] = 0.f; }
    float racc = 0.f;

#pragma unroll 1
    for (int quad = 0; quad < 4; ++quad) {
        const int ibase = g + 256*quad;          // i = ibase + 64*m

        float z[4][8];
#pragma unroll
        for (int m = 0; m < 4; ++m)
#pragma unroll
            for (int u = 0; u < 8; ++u) z[m][u] = sB[c0+u];

        // ---- r feature (computed redundantly by the 4 q-lanes) ----
        float rv[4];
#pragma unroll
        for (int m = 0; m < 4; ++m) {
            const int i = ibase + 64*m;
            float r2 = 0.f;
#pragma unroll
            for (int d = 0; d < 3; ++d) {
                float2 piv = TP2[d*NP + i];               // (cp_i, sp_i)
                float sd = fmaf(piv.y, sJ[48+d], -(piv.x * sJ[51+d]));
                r2 = fmaf(sd, sd, r2);
            }
            rv[m] = sqrtf(r2);
            racc += rv[m];
        }
        {
            const float4* w = (const float4*)(sW0 + c0);  // row 0
            float4 wa = w[0], wb = w[1];
#pragma unroll
            for (int m = 0; m < 4; ++m) {
                z[m][0]=fmaf(rv[m],wa.x,z[m][0]); z[m][1]=fmaf(rv[m],wa.y,z[m][1]);
                z[m][2]=fmaf(rv[m],wa.z,z[m][2]); z[m][3]=fmaf(rv[m],wa.w,z[m][3]);
                z[m][4]=fmaf(rv[m],wb.x,z[m][4]); z[m][5]=fmaf(rv[m],wb.y,z[m][5]);
                z[m][6]=fmaf(rv[m],wb.z,z[m][6]); z[m][7]=fmaf(rv[m],wb.w,z[m][7]);
            }
        }
        // ---- 48 cos/sin features ----
#pragma unroll
        for (int kd = 0; kd < 24; ++kd) {
            const float ckj = sJ[kd], skj = sJ[24+kd];
            float cc[4], ss[4];
#pragma unroll
            for (int m = 0; m < 4; ++m) {
                float2 cs = TCS[kd*NP + ibase + 64*m];    // (c_i, s_i)
                cc[m] = fmaf(cs.x, ckj, cs.y * skj);
                ss[m] = fmaf(cs.y, ckj, -(cs.x * skj));
            }
            const int k = kd / 3, d = kd - k*3;
            const float4* wc  = (const float4*)(sW0 + (1 + k*6 + d)*32 + c0);
            const float4* wsn = (const float4*)(sW0 + (4 + k*6 + d)*32 + c0);
            float4 ca = wc[0],  cb = wc[1];
            float4 sa = wsn[0], sb = wsn[1];
#pragma unroll
            for (int m = 0; m < 4; ++m) {
                z[m][0]=fmaf(cc[m],ca.x,fmaf(ss[m],sa.x,z[m][0]));
                z[m][1]=fmaf(cc[m],ca.y,fmaf(ss[m],sa.y,z[m][1]));
                z[m][2]=fmaf(cc[m],ca.z,fmaf(ss[m],sa.z,z[m][2]));
                z[m][3]=fmaf(cc[m],ca.w,fmaf(ss[m],sa.w,z[m][3]));
                z[m][4]=fmaf(cc[m],cb.x,fmaf(ss[m],sb.x,z[m][4]));
                z[m][5]=fmaf(cc[m],cb.y,fmaf(ss[m],sb.y,z[m][5]));
                z[m][6]=fmaf(cc[m],cb.z,fmaf(ss[m],sb.z,z[m][6]));
                z[m][7]=fmaf(cc[m],cb.w,fmaf(ss[m],sb.w,z[m][7]));
            }
        }

        // ---- layer 0 tanh ----
        float h0[4][8];
#pragma unroll
        for (int m = 0; m < 4; ++m)
#pragma unroll
            for (int u = 0; u < 8; ++u) {
                float h = ftanh(z[m][u]);
                h0[m][u] = h; a0[u] += h;
                z[m][u] = sB[32 + c0 + u];
            }

        // ---- layer 1: z += h0_full(32) @ W1[:, my 8 cols]; shfl exchange ----
#pragma unroll
        for (int p = 0; p < 4; ++p) {
            const int kq = ((q ^ p) * 8);
#pragma unroll
            for (int u0 = 0; u0 < 8; ++u0) {
                float hv[4];
#pragma unroll
                for (int m = 0; m < 4; ++m)
                    hv[m] = (p == 0) ? h0[m][u0] : __shfl_xor(h0[m][u0], p, 64);
                const float4* wr = (const float4*)(sW1 + (kq + u0)*32 + c0);
                float4 wa = wr[0], wb = wr[1];
#pragma unroll
                for (int m = 0; m < 4; ++m) {
                    z[m][0]=fmaf(hv[m],wa.x,z[m][0]); z[m][1]=fmaf(hv[m],wa.y,z[m][1]);
                    z[m][2]=fmaf(hv[m],wa.z,z[m][2]); z[m][3]=fmaf(hv[m],wa.w,z[m][3]);
                    z[m][4]=fmaf(hv[m],wb.x,z[m][4]); z[m][5]=fmaf(hv[m],wb.y,z[m][5]);
                    z[m][6]=fmaf(hv[m],wb.z,z[m][6]); z[m][7]=fmaf(hv[m],wb.w,z[m][7]);
                }
            }
        }
        float h1v[4][8];
#pragma unroll
        for (int m = 0; m < 4; ++m)
#pragma unroll
            for (int u = 0; u < 8; ++u) {
                float h = ftanh(z[m][u]) + h0[m][u];      // residual
                h1v[m][u] = h; a1[u] += h;
                z[m][u] = sB[64 + c0 + u];
            }

        // ---- layer 2 ----
#pragma unroll
        for (int p = 0; p < 4; ++p) {
            const int kq = ((q ^ p) * 8);
#pragma unroll
            for (int u0 = 0; u0 < 8; ++u0) {
                float hv[4];
#pragma unroll
                for (int m = 0; m < 4; ++m)
                    hv[m] = (p == 0) ? h1v[m][u0] : __shfl_xor(h1v[m][u0], p, 64);
                const float4* wr = (const float4*)(sW2 + (kq + u0)*32 + c0);
                float4 wa = wr[0], wb = wr[1];
#pragma unroll
                for (int m = 0; m < 4; ++m) {
                    z[m][0]=fmaf(hv[m],wa.x,z[m][0]); z[m][1]=fmaf(hv[m],wa.y,z[m][1]);
                    z[m][2]=fmaf(hv[m],wa.z,z[m][2]); z[m][3]=fmaf(hv[m],wa.w,z[m][3]);
                    z[m][4]=fmaf(hv[m],wb.x,z[m][4]); z[m][5]=fmaf(hv[m],wb.y,z[m][5]);
                    z[m][6]=fmaf(hv[m],wb.z,z[m][6]); z[m][7]=fmaf(hv[m],wb.w,z[m][7]);
                }
            }
        }
#pragma unroll
        for (int m = 0; m < 4; ++m)
#pragma unroll
            for (int u = 0; u < 8; ++u)
                a2[u] += ftanh(z[m][u]) + h1v[m][u];
    }

    // ---- reduction ----
    const int lane = tid & 63, wid = tid >> 6;
#pragma unroll
    for (int mask = 1; mask < 64; mask <<= 1) racc += __shfl_xor(racc, mask, 64);
#pragma unroll
    for (int u = 0; u < 8; ++u)
#pragma unroll
        for (int mask = 4; mask < 64; mask <<= 1) {
            a0[u] += __shfl_xor(a0[u], mask, 64);
            a1[u] += __shfl_xor(a1[u], mask, 64);
            a2[u] += __shfl_xor(a2[u], mask, 64);
        }
    if (lane == 0) sPart[wid][0] = racc;
    if (lane < 4) {
#pragma unroll
        for (int u = 0; u < 8; ++u) {
            sPart[wid][1  + lane*8 + u] = a0[u];
            sPart[wid][33 + lane*8 + u] = a1[u];
            sPart[wid][65 + lane*8 + u] = a2[u];
        }
    }
    __syncthreads();
    if (tid < 97) {
        float s = sPart[0][tid] + sPart[1][tid] + sPart[2][tid] + sPart[3][tid];
        if (tid == 0)      RACC[j] = s * 0.25f;      // r computed 4x redundantly
        else if (tid < 33) M0[j*32 + (tid-1)]  = s;
        else if (tid < 65) M1[j*32 + (tid-33)] = s;
        else               M2[j*32 + (tid-65)] = s;
    }
}

// ---------------------------------------------------------------------------
// Phase B: h1 path. Thread = (row j, 8-channel chunk q). 8192 threads.
// ---------------------------------------------------------------------------
#define FMA8(fv, wptr) do { \
    const float4* w4_ = (const float4*)(wptr); \
    float4 a_ = w4_[0], b_ = w4_[1]; \
    z[0]=fmaf((fv),a_.x,z[0]); z[1]=fmaf((fv),a_.y,z[1]); \
    z[2]=fmaf((fv),a_.z,z[2]); z[3]=fmaf((fv),a_.w,z[3]); \
    z[4]=fmaf((fv),b_.x,z[4]); z[5]=fmaf((fv),b_.y,z[5]); \
    z[6]=fmaf((fv),b_.z,z[6]); z[7]=fmaf((fv),b_.w,z[7]); \
} while (0)

// wave-reduce 8 per-channel values over the 8 rows in this wave, then one
// atomicAdd per (wave, channel) -- 8x fewer global atomics than per-thread.
__device__ __forceinline__ void hsum_atomic(float* HS, const float h[8],
                                            int tid, int c0) {
    float hs[8];
#pragma unroll
    for (int u = 0; u < 8; ++u) {
        hs[u] = h[u];
#pragma unroll
        for (int mask = 8; mask < 64; mask <<= 1)
            hs[u] += __shfl_xor(hs[u], mask, 64);
    }
    if (((tid & 63) >> 3) == 0) {
#pragma unroll
        for (int u = 0; u < 8; ++u) atomicAdd(&HS[c0 + u], hs[u]);
    }
}

__global__ __launch_bounds__(256) void l0_kernel(
    const float* __restrict__ Tsc, const float* __restrict__ W10,
    const float* __restrict__ b10,
    const float2* __restrict__ TCS,
    const float* __restrict__ CSUM, const float* __restrict__ SSUM,
    const float* __restrict__ RACC,
    float* __restrict__ H1A, float* __restrict__ HSUM0)
{
    const int tid = threadIdx.x;
    const int gid = blockIdx.x*256 + tid;
    const int j = gid >> 3, qq = gid & 7, c0 = qq*8;
    const float inv_n = 1.0f/1024.0f;
    const float t = Tsc[0];

    float z[8];
#pragma unroll
    for (int u = 0; u < 8; ++u) z[u] = b10[c0+u];

    FMA8(t, W10 + 0*64 + c0);
    FMA8(t, W10 + 17*64 + c0);
#pragma unroll
    for (int k = 0; k < 8; ++k) {
        float s, c; sincospif(2.0f*(float)(k+1)*t, &s, &c);
        FMA8(c, W10 + (1+2*k)*64 + c0);
        FMA8(c, W10 + (18+2*k)*64 + c0);
        FMA8(s, W10 + (2+2*k)*64 + c0);
        FMA8(s, W10 + (19+2*k)*64 + c0);
    }
    {
        float rb = RACC[j] * inv_n;
        FMA8(rb, W10 + 34*64 + c0);
    }
#pragma unroll
    for (int kd = 0; kd < 24; ++kd) {
        float2 cs = TCS[kd*NP + j];
        float Cb = CSUM[kd]*inv_n, Sb = SSUM[kd]*inv_n;
        float cm = fmaf(cs.x, Cb, cs.y*Sb);
        float sm = fmaf(Sb, cs.x, -(Cb*cs.y));
        int k = kd/3, d = kd - k*3;
        FMA8(cm, W10 + (35 + k*6 + d)*64 + c0);
        FMA8(sm, W10 + (38 + k*6 + d)*64 + c0);
    }
    float h[8];
#pragma unroll
    for (int u = 0; u < 8; ++u) {
        h[u] = ftanh(z[u]);                  // layer 0: no residual
        H1A[j*64 + c0 + u] = h[u];
    }
    hsum_atomic(HSUM0, h, tid, c0);
}

template<int LAYER>
__global__ __launch_bounds__(256) void lx_kernel(
    const float* __restrict__ W, const float* __restrict__ b,
    const float* __restrict__ hin, float* __restrict__ hout,
    const float* __restrict__ HSin, float* __restrict__ HSout,
    const float* __restrict__ M,
    const float* __restrict__ Wf, const float* __restrict__ X,
    float* __restrict__ out)
{
    const int tid = threadIdx.x;
    const int gid = blockIdx.x*256 + tid;
    const int j = gid >> 3, qq = gid & 7, c0 = qq*8;
    const float inv_n = 1.0f/1024.0f;

    float z[8];
#pragma unroll
    for (int u = 0; u < 8; ++u) z[u] = b[c0+u];
    const float* hrow = hin + j*64;
#pragma unroll 4
    for (int p = 0; p < 64; ++p) {
        float fv = hrow[p];
        FMA8(fv, W + p*64 + c0);
    }
#pragma unroll 4
    for (int p = 0; p < 64; ++p) {
        float fv = HSin[p] * inv_n;
        FMA8(fv, W + (64+p)*64 + c0);
    }
    const float* mrow = M + j*32;
#pragma unroll 4
    for (int p = 0; p < 32; ++p) {
        float fv = mrow[p] * inv_n;
        FMA8(fv, W + (128+p)*64 + c0);
    }
    float h[8];
#pragma unroll
    for (int u = 0; u < 8; ++u) h[u] = ftanh(z[u]) + hrow[c0+u];  // residual

    if (LAYER < 3) {
#pragma unroll
        for (int u = 0; u < 8; ++u) hout[j*64 + c0 + u] = h[u];
        hsum_atomic(HSout, h, tid, c0);
    } else {
        __shared__ float red[256][3];
        float p0 = 0.f, p1 = 0.f, p2 = 0.f;
#pragma unroll
        for (int u = 0; u < 8; ++u) {
            float hv = h[u];
            const float* wf = Wf + (c0+u)*3;
            p0 = fmaf(hv, wf[0], p0);
            p1 = fmaf(hv, wf[1], p1);
            p2 = fmaf(hv, wf[2], p2);
        }
        red[tid][0] = p0; red[tid][1] = p1; red[tid][2] = p2;
        __syncthreads();
        if (qq == 0) {
            float s0 = 0.f, s1 = 0.f, s2 = 0.f;
#pragma unroll
            for (int r = 0; r < 8; ++r) {
                s0 += red[tid+r][0]; s1 += red[tid+r][1]; s2 += red[tid+r][2];
            }
#pragma unroll
            for (int d = 0; d < 3; ++d) {
                float fx = 2.0f * X[j*3 + d];
                fx = fminf(fmaxf(fx, -10.0f), 10.0f);
                float s = (d == 0 ? s0 : (d == 1 ? s1 : s2));
                out[j*3 + d] = -s * fx;
            }
        }
    }
}

// ---------------------------------------------------------------------------
extern "C" void kernel_launch(void* const* d_in, const int* in_sizes, int n_in,
                              void* d_out, int out_size, void* d_ws, size_t ws_size,
                              hipStream_t stream)
{
    const float* X   = (const float*)d_in[0];
    const float* Tsc = (const float*)d_in[1];
    const float* W10 = (const float*)d_in[2];  const float* b10 = (const float*)d_in[3];
    const float* W11 = (const float*)d_in[4];  const float* b11 = (const float*)d_in[5];
    const float* W12 = (const float*)d_in[6];  const float* b12 = (const float*)d_in[7];
    const float* W13 = (const float*)d_in[8];  const float* b13 = (const float*)d_in[9];
    const float* W20 = (const float*)d_in[10]; const float* b20 = (const float*)d_in[11];
    const float* W21 = (const float*)d_in[12]; const float* b21 = (const float*)d_in[13];
    const float* W22 = (const float*)d_in[14]; const float* b22 = (const float*)d_in[15];
    const float* Wf  = (const float*)d_in[16];

    float* ws  = (float*)d_ws;
    float* out = (float*)d_out;

    float2* TCS = (float2*)(ws + OF_TCS);
    float2* TP2 = (float2*)(ws + OF_TP2);
    float* CSUM = ws + OF_CSUM; float* SSUM = ws + OF_SSUM;
    float* HSUM = ws + OF_HSUM; float* RACC = ws + OF_RACC;
    float* M0 = ws + OF_M0; float* M1 = ws + OF_M1; float* M2 = ws + OF_M2;
    float* H1A = ws + OF_H1A; float* H1B = ws + OF_H1B;

    k1_tables<<<1, 1024, 0, stream>>>(X, TCS, TP2, CSUM, SSUM, HSUM);
    k2_pairs<<<NP, 256, 0, stream>>>(W20, b20, W21, b21, W22, b22,
                                     TCS, TP2, RACC, M0, M1, M2);
    l0_kernel<<<32, 256, 0, stream>>>(Tsc, W10, b10, TCS, CSUM, SSUM, RACC,
                                      H1A, HSUM + 0*64);
    lx_kernel<1><<<32, 256, 0, stream>>>(W11, b11, H1A, H1B, HSUM + 0*64, HSUM + 1*64,
                                         M0, (const float*)nullptr, (const float*)nullptr,
                                         (float*)nullptr);
    lx_kernel<2><<<32, 256, 0, stream>>>(W12, b12, H1B, H1A, HSUM + 1*64, HSUM + 2*64,
                                         M1, (const float*)nullptr, (const float*)nullptr,
                                         (float*)nullptr);
    lx_kernel<3><<<32, 256, 0, stream>>>(W13, b13, H1A, H1B, HSUM + 2*64, (float*)nullptr,
                                         M2, Wf, X, out);
}

// Round 3
// 730.078 us; speedup vs baseline: 7.0040x; 1.9458x over previous
//
#include <hip/hip_runtime.h>
#include <math.h>

// FermiNet-like forward, N=1024, DIM=3, all fp32.
//
// v3: kill the residual scratch traffic seen in v2 (FETCH 1.9GB / WRITE 1.0GB
// despite VGPR_Count=84 -> compiler spilled under the (256,3) cap with ~150
// live floats). Restructure k2_pairs:
//   * 8-lane channel groups (4 cols/lane), m=4 i's/thread, 8 outer iters.
//     Live state ~90 floats -> no spill possible. __launch_bounds__(256,2).
//   * h0/h1 exchanged via XOR-swizzled LDS tile sH (float4 slots, slot^= g&7)
//     instead of 770 shuffles/thread. Conflict-free reads; producer/consumer
//     is within one wave -> no barriers in the main loop.
//   * Weight float4 reads are 8-way broadcast + contiguous -> conflict-free.
// Math identical to v2 (PASSED, absmax 9.5e-7).

#define NP 1024

// ---- workspace offsets (in floats) ----
static const size_t OF_TCS  = 0;                   // float2[24*NP] (cos,sin) 2pi k x_d
static const size_t OF_TP2  = OF_TCS + 48*NP;      // float2[3*NP]  (cos,sin) pi x_d
static const size_t OF_CSUM = OF_TP2 + 6*NP;       // 24  sum_i cos
static const size_t OF_SSUM = OF_CSUM + 24;        // 24  sum_i sin
static const size_t OF_HSUM = OF_SSUM + 24;        // 3*64  h1 row-sum per layer
static const size_t OF_RACC = OF_HSUM + 192;       // 1024  sum_i r(i,j)
static const size_t OF_M0   = OF_RACC + NP;        // 1024*32 sum_i h2 stage0
static const size_t OF_M1   = OF_M0 + NP*32;       // 1024*32 stage1
static const size_t OF_M2   = OF_M1 + NP*32;       // 1024*32 stage2
static const size_t OF_H1A  = OF_M2 + NP*32;       // 1024*64
static const size_t OF_H1B  = OF_H1A + NP*64;      // 1024*64
// end: OF_H1B + NP*64 = 285936 floats (~1.15 MB)

__device__ __forceinline__ float ftanh(float x) {
    float e = __expf(2.0f * x);
    return 1.0f - __fdividef(2.0f, e + 1.0f);
}

// ---------------------------------------------------------------------------
// K1: per-particle trig tables (interleaved float2) + column sums + zero HSUM.
// ---------------------------------------------------------------------------
__global__ __launch_bounds__(1024) void k1_tables(
    const float* __restrict__ X,
    float2* __restrict__ TCS, float2* __restrict__ TP2,
    float* __restrict__ CSUM, float* __restrict__ SSUM,
    float* __restrict__ HSUM)
{
    const int i = threadIdx.x;
    float ck[24], sk[24];
#pragma unroll
    for (int d = 0; d < 3; ++d) {
        float x = X[i*3 + d];
        float sp, cp;
        sincospif(x, &sp, &cp);
        TP2[d*NP + i] = make_float2(cp, sp);
#pragma unroll
        for (int k = 0; k < 8; ++k) {
            float s, c;
            sincospif(2.0f*(float)(k+1)*x, &s, &c);
            ck[k*3 + d] = c;  sk[k*3 + d] = s;
            TCS[(k*3 + d)*NP + i] = make_float2(c, s);
        }
    }
    __shared__ float part[48*16];
    const int lane = i & 63, wv = i >> 6;
#pragma unroll
    for (int v = 0; v < 24; ++v) {
        float a = ck[v], b = sk[v];
#pragma unroll
        for (int off = 32; off; off >>= 1) {
            a += __shfl_down(a, off, 64);
            b += __shfl_down(b, off, 64);
        }
        if (lane == 0) { part[v*16 + wv] = a; part[(24+v)*16 + wv] = b; }
    }
    __syncthreads();
    if (i < 48) {
        float s = 0.f;
#pragma unroll
        for (int w = 0; w < 16; ++w) s += part[i*16 + w];
        if (i < 24) CSUM[i] = s; else SSUM[i-24] = s;
    }
    if (i < 192) HSUM[i] = 0.0f;
}

// ---------------------------------------------------------------------------
// K2: pair kernel. Block = column j. q = tid&7 (cols q*4..q*4+3), g = tid>>3.
// i = it*128 + m*32 + g, m=0..3, it=0..7. No barriers in the main loop.
// ---------------------------------------------------------------------------
__global__ __launch_bounds__(256, 2) void k2_pairs(
    const float* __restrict__ W20, const float* __restrict__ b20,
    const float* __restrict__ W21, const float* __restrict__ b21,
    const float* __restrict__ W22, const float* __restrict__ b22,
    const float2* __restrict__ TCS, const float2* __restrict__ TP2,
    float* __restrict__ RACC, float* __restrict__ M0,
    float* __restrict__ M1, float* __restrict__ M2)
{
    __shared__ __align__(16) float sW0[49*32];
    __shared__ __align__(16) float sW1[32*32];
    __shared__ __align__(16) float sW2[32*32];
    __shared__ __align__(16) float sH[4*32*32];   // float4 slots, XOR-swizzled
    __shared__ float sB[96];
    __shared__ float sJ[54];    // [0..23] c_j, [24..47] s_j, [48..50] cp_j, [51..53] sp_j
    __shared__ float sPart[4][97];

    const int tid = threadIdx.x;
    const int j = blockIdx.x;
    const int q = tid & 7;
    const int g = tid >> 3;
    const int c0 = q * 4;
    const int gx = g & 7;

    for (int v = tid; v < 49*32; v += 256) sW0[v] = W20[v];
    for (int v = tid; v < 32*32; v += 256) sW1[v] = W21[v];
    for (int v = tid; v < 32*32; v += 256) sW2[v] = W22[v];
    if (tid < 32) { sB[tid] = b20[tid]; sB[32+tid] = b21[tid]; sB[64+tid] = b22[tid]; }
    if (tid < 24) { float2 cs = TCS[tid*NP + j]; sJ[tid] = cs.x; sJ[24+tid] = cs.y; }
    if (tid < 3)  { float2 pv = TP2[tid*NP + j]; sJ[48+tid] = pv.x; sJ[51+tid] = pv.y; }
    __syncthreads();

    float4* sH4 = (float4*)sH;        // index: (m*32+g)*8 + (slot ^ gx)

    float a0[4], a1[4], a2[4];
#pragma unroll
    for (int u = 0; u < 4; ++u) { a0[u] = 0.f; a1[u] = 0.f; a2[u] = 0.f; }
    float racc = 0.f;

#pragma unroll 1
    for (int it = 0; it < 8; ++it) {
        const int ib = it*128 + g;            // + m*32 -> i
        const float2* tp = TP2 + ib;
        const float2* tc = TCS + ib;

        float z[4][4];
#pragma unroll
        for (int m = 0; m < 4; ++m) {
            z[m][0] = sB[c0+0]; z[m][1] = sB[c0+1];
            z[m][2] = sB[c0+2]; z[m][3] = sB[c0+3];
        }

        // ---- r feature (8x redundant across q-lanes) ----
        float rv[4];
#pragma unroll
        for (int m = 0; m < 4; ++m) {
            float r2 = 0.f;
#pragma unroll
            for (int d = 0; d < 3; ++d) {
                float2 pv = tp[d*NP + m*32];
                float sd = fmaf(pv.y, sJ[48+d], -(pv.x * sJ[51+d]));
                r2 = fmaf(sd, sd, r2);
            }
            rv[m] = sqrtf(r2);
            racc += rv[m];
        }
        {
            const float4 w = *(const float4*)(sW0 + c0);   // row 0
#pragma unroll
            for (int m = 0; m < 4; ++m) {
                z[m][0]=fmaf(rv[m],w.x,z[m][0]); z[m][1]=fmaf(rv[m],w.y,z[m][1]);
                z[m][2]=fmaf(rv[m],w.z,z[m][2]); z[m][3]=fmaf(rv[m],w.w,z[m][3]);
            }
        }
        // ---- 48 cos/sin features ----
#pragma unroll
        for (int kd = 0; kd < 24; ++kd) {
            const int k = kd/3, d = kd - k*3;
            const float ckj = sJ[kd], skj = sJ[24+kd];
            const float4 wc  = *(const float4*)(sW0 + (1 + k*6 + d)*32 + c0);
            const float4 wsn = *(const float4*)(sW0 + (4 + k*6 + d)*32 + c0);
#pragma unroll
            for (int m = 0; m < 4; ++m) {
                float2 cs = tc[kd*NP + m*32];
                float cc = fmaf(cs.x, ckj, cs.y * skj);
                float ss = fmaf(cs.y, ckj, -(cs.x * skj));
                z[m][0] = fmaf(cc, wc.x, fmaf(ss, wsn.x, z[m][0]));
                z[m][1] = fmaf(cc, wc.y, fmaf(ss, wsn.y, z[m][1]));
                z[m][2] = fmaf(cc, wc.z, fmaf(ss, wsn.z, z[m][2]));
                z[m][3] = fmaf(cc, wc.w, fmaf(ss, wsn.w, z[m][3]));
            }
        }

        // ---- layer 0 tanh; publish h0 to sH ----
        float h0own[4][4];
#pragma unroll
        for (int m = 0; m < 4; ++m) {
            float4 hv;
            hv.x = ftanh(z[m][0]); hv.y = ftanh(z[m][1]);
            hv.z = ftanh(z[m][2]); hv.w = ftanh(z[m][3]);
            h0own[m][0]=hv.x; h0own[m][1]=hv.y; h0own[m][2]=hv.z; h0own[m][3]=hv.w;
            a0[0]+=hv.x; a0[1]+=hv.y; a0[2]+=hv.z; a0[3]+=hv.w;
            sH4[(m*32+g)*8 + (q ^ gx)] = hv;
            z[m][0]=sB[32+c0+0]; z[m][1]=sB[32+c0+1];
            z[m][2]=sB[32+c0+2]; z[m][3]=sB[32+c0+3];
        }

        // ---- layer 1 matvec (reads sH written by own wave-group) ----
#pragma unroll
        for (int kc = 0; kc < 8; ++kc) {
            const float4 w0 = *(const float4*)(sW1 + (kc*4+0)*32 + c0);
            const float4 w1 = *(const float4*)(sW1 + (kc*4+1)*32 + c0);
            const float4 w2 = *(const float4*)(sW1 + (kc*4+2)*32 + c0);
            const float4 w3 = *(const float4*)(sW1 + (kc*4+3)*32 + c0);
#pragma unroll
            for (int m = 0; m < 4; ++m) {
                const float4 hc = sH4[(m*32+g)*8 + (kc ^ gx)];
                z[m][0]=fmaf(hc.x,w0.x,fmaf(hc.y,w1.x,fmaf(hc.z,w2.x,fmaf(hc.w,w3.x,z[m][0]))));
                z[m][1]=fmaf(hc.x,w0.y,fmaf(hc.y,w1.y,fmaf(hc.z,w2.y,fmaf(hc.w,w3.y,z[m][1]))));
                z[m][2]=fmaf(hc.x,w0.z,fmaf(hc.y,w1.z,fmaf(hc.z,w2.z,fmaf(hc.w,w3.z,z[m][2]))));
                z[m][3]=fmaf(hc.x,w0.w,fmaf(hc.y,w1.w,fmaf(hc.z,w2.w,fmaf(hc.w,w3.w,z[m][3]))));
            }
        }
        float h1own[4][4];
#pragma unroll
        for (int m = 0; m < 4; ++m) {
            float4 hv;
            hv.x = ftanh(z[m][0]) + h0own[m][0];
            hv.y = ftanh(z[m][1]) + h0own[m][1];
            hv.z = ftanh(z[m][2]) + h0own[m][2];
            hv.w = ftanh(z[m][3]) + h0own[m][3];
            h1own[m][0]=hv.x; h1own[m][1]=hv.y; h1own[m][2]=hv.z; h1own[m][3]=hv.w;
            a1[0]+=hv.x; a1[1]+=hv.y; a1[2]+=hv.z; a1[3]+=hv.w;
            sH4[(m*32+g)*8 + (q ^ gx)] = hv;       // overwrite h0 (reads done)
            z[m][0]=sB[64+c0+0]; z[m][1]=sB[64+c0+1];
            z[m][2]=sB[64+c0+2]; z[m][3]=sB[64+c0+3];
        }

        // ---- layer 2 matvec ----
#pragma unroll
        for (int kc = 0; kc < 8; ++kc) {
            const float4 w0 = *(const float4*)(sW2 + (kc*4+0)*32 + c0);
            const float4 w1 = *(const float4*)(sW2 + (kc*4+1)*32 + c0);
            const float4 w2 = *(const float4*)(sW2 + (kc*4+2)*32 + c0);
            const float4 w3 = *(const float4*)(sW2 + (kc*4+3)*32 + c0);
#pragma unroll
            for (int m = 0; m < 4; ++m) {
                const float4 hc = sH4[(m*32+g)*8 + (kc ^ gx)];
                z[m][0]=fmaf(hc.x,w0.x,fmaf(hc.y,w1.x,fmaf(hc.z,w2.x,fmaf(hc.w,w3.x,z[m][0]))));
                z[m][1]=fmaf(hc.x,w0.y,fmaf(hc.y,w1.y,fmaf(hc.z,w2.y,fmaf(hc.w,w3.y,z[m][1]))));
                z[m][2]=fmaf(hc.x,w0.z,fmaf(hc.y,w1.z,fmaf(hc.z,w2.z,fmaf(hc.w,w3.z,z[m][2]))));
                z[m][3]=fmaf(hc.x,w0.w,fmaf(hc.y,w1.w,fmaf(hc.z,w2.w,fmaf(hc.w,w3.w,z[m][3]))));
            }
        }
#pragma unroll
        for (int m = 0; m < 4; ++m) {
            a2[0] += ftanh(z[m][0]) + h1own[m][0];
            a2[1] += ftanh(z[m][1]) + h1own[m][1];
            a2[2] += ftanh(z[m][2]) + h1own[m][2];
            a2[3] += ftanh(z[m][3]) + h1own[m][3];
        }
    }

    // ---- reduction: over g within wave, then across 4 waves via LDS ----
    const int lane = tid & 63, wid = tid >> 6;
#pragma unroll
    for (int u = 0; u < 4; ++u) {
#pragma unroll
        for (int mask = 8; mask < 64; mask <<= 1) {
            a0[u] += __shfl_xor(a0[u], mask, 64);
            a1[u] += __shfl_xor(a1[u], mask, 64);
            a2[u] += __shfl_xor(a2[u], mask, 64);
        }
    }
#pragma unroll
    for (int mask = 1; mask < 64; mask <<= 1) racc += __shfl_xor(racc, mask, 64);

    if (lane < 8) {
#pragma unroll
        for (int u = 0; u < 4; ++u) {
            sPart[wid][1  + lane*4 + u] = a0[u];
            sPart[wid][33 + lane*4 + u] = a1[u];
            sPart[wid][65 + lane*4 + u] = a2[u];
        }
    }
    if (lane == 0) sPart[wid][0] = racc;
    __syncthreads();
    if (tid < 97) {
        float s = sPart[0][tid] + sPart[1][tid] + sPart[2][tid] + sPart[3][tid];
        if (tid == 0)      RACC[j] = s * 0.125f;     // r computed 8x redundantly
        else if (tid < 33) M0[j*32 + (tid-1)]  = s;
        else if (tid < 65) M1[j*32 + (tid-33)] = s;
        else               M2[j*32 + (tid-65)] = s;
    }
}

// ---------------------------------------------------------------------------
// Phase B: h1 path. Thread = (row j, 8-channel chunk q). 8192 threads.
// ---------------------------------------------------------------------------
#define FMA8(fv, wptr) do { \
    const float4* w4_ = (const float4*)(wptr); \
    float4 a_ = w4_[0], b_ = w4_[1]; \
    z[0]=fmaf((fv),a_.x,z[0]); z[1]=fmaf((fv),a_.y,z[1]); \
    z[2]=fmaf((fv),a_.z,z[2]); z[3]=fmaf((fv),a_.w,z[3]); \
    z[4]=fmaf((fv),b_.x,z[4]); z[5]=fmaf((fv),b_.y,z[5]); \
    z[6]=fmaf((fv),b_.z,z[6]); z[7]=fmaf((fv),b_.w,z[7]); \
} while (0)

__device__ __forceinline__ void hsum_atomic(float* HS, const float h[8],
                                            int tid, int c0) {
    float hs[8];
#pragma unroll
    for (int u = 0; u < 8; ++u) {
        hs[u] = h[u];
#pragma unroll
        for (int mask = 8; mask < 64; mask <<= 1)
            hs[u] += __shfl_xor(hs[u], mask, 64);
    }
    if (((tid & 63) >> 3) == 0) {
#pragma unroll
        for (int u = 0; u < 8; ++u) atomicAdd(&HS[c0 + u], hs[u]);
    }
}

__global__ __launch_bounds__(256) void l0_kernel(
    const float* __restrict__ Tsc, const float* __restrict__ W10,
    const float* __restrict__ b10,
    const float2* __restrict__ TCS,
    const float* __restrict__ CSUM, const float* __restrict__ SSUM,
    const float* __restrict__ RACC,
    float* __restrict__ H1A, float* __restrict__ HSUM0)
{
    const int tid = threadIdx.x;
    const int gid = blockIdx.x*256 + tid;
    const int j = gid >> 3, qq = gid & 7, c0 = qq*8;
    const float inv_n = 1.0f/1024.0f;
    const float t = Tsc[0];

    float z[8];
#pragma unroll
    for (int u = 0; u < 8; ++u) z[u] = b10[c0+u];

    FMA8(t, W10 + 0*64 + c0);
    FMA8(t, W10 + 17*64 + c0);
#pragma unroll
    for (int k = 0; k < 8; ++k) {
        float s, c; sincospif(2.0f*(float)(k+1)*t, &s, &c);
        FMA8(c, W10 + (1+2*k)*64 + c0);
        FMA8(c, W10 + (18+2*k)*64 + c0);
        FMA8(s, W10 + (2+2*k)*64 + c0);
        FMA8(s, W10 + (19+2*k)*64 + c0);
    }
    {
        float rb = RACC[j] * inv_n;
        FMA8(rb, W10 + 34*64 + c0);
    }
#pragma unroll
    for (int kd = 0; kd < 24; ++kd) {
        float2 cs = TCS[kd*NP + j];
        float Cb = CSUM[kd]*inv_n, Sb = SSUM[kd]*inv_n;
        float cm = fmaf(cs.x, Cb, cs.y*Sb);
        float sm = fmaf(Sb, cs.x, -(Cb*cs.y));
        int k = kd/3, d = kd - k*3;
        FMA8(cm, W10 + (35 + k*6 + d)*64 + c0);
        FMA8(sm, W10 + (38 + k*6 + d)*64 + c0);
    }
    float h[8];
#pragma unroll
    for (int u = 0; u < 8; ++u) {
        h[u] = ftanh(z[u]);                  // layer 0: no residual
        H1A[j*64 + c0 + u] = h[u];
    }
    hsum_atomic(HSUM0, h, tid, c0);
}

template<int LAYER>
__global__ __launch_bounds__(256) void lx_kernel(
    const float* __restrict__ W, const float* __restrict__ b,
    const float* __restrict__ hin, float* __restrict__ hout,
    const float* __restrict__ HSin, float* __restrict__ HSout,
    const float* __restrict__ M,
    const float* __restrict__ Wf, const float* __restrict__ X,
    float* __restrict__ out)
{
    const int tid = threadIdx.x;
    const int gid = blockIdx.x*256 + tid;
    const int j = gid >> 3, qq = gid & 7, c0 = qq*8;
    const float inv_n = 1.0f/1024.0f;

    float z[8];
#pragma unroll
    for (int u = 0; u < 8; ++u) z[u] = b[c0+u];
    const float* hrow = hin + j*64;
#pragma unroll 4
    for (int p = 0; p < 64; ++p) {
        float fv = hrow[p];
        FMA8(fv, W + p*64 + c0);
    }
#pragma unroll 4
    for (int p = 0; p < 64; ++p) {
        float fv = HSin[p] * inv_n;
        FMA8(fv, W + (64+p)*64 + c0);
    }
    const float* mrow = M + j*32;
#pragma unroll 4
    for (int p = 0; p < 32; ++p) {
        float fv = mrow[p] * inv_n;
        FMA8(fv, W + (128+p)*64 + c0);
    }
    float h[8];
#pragma unroll
    for (int u = 0; u < 8; ++u) h[u] = ftanh(z[u]) + hrow[c0+u];  // residual

    if (LAYER < 3) {
#pragma unroll
        for (int u = 0; u < 8; ++u) hout[j*64 + c0 + u] = h[u];
        hsum_atomic(HSout, h, tid, c0);
    } else {
        __shared__ float red[256][3];
        float p0 = 0.f, p1 = 0.f, p2 = 0.f;
#pragma unroll
        for (int u = 0; u < 8; ++u) {
            float hv = h[u];
            const float* wf = Wf + (c0+u)*3;
            p0 = fmaf(hv, wf[0], p0);
            p1 = fmaf(hv, wf[1], p1);
            p2 = fmaf(hv, wf[2], p2);
        }
        red[tid][0] = p0; red[tid][1] = p1; red[tid][2] = p2;
        __syncthreads();
        if (qq == 0) {
            float s0 = 0.f, s1 = 0.f, s2 = 0.f;
#pragma unroll
            for (int r = 0; r < 8; ++r) {
                s0 += red[tid+r][0]; s1 += red[tid+r][1]; s2 += red[tid+r][2];
            }
#pragma unroll
            for (int d = 0; d < 3; ++d) {
                float fx = 2.0f * X[j*3 + d];
                fx = fminf(fmaxf(fx, -10.0f), 10.0f);
                float s = (d == 0 ? s0 : (d == 1 ? s1 : s2));
                out[j*3 + d] = -s * fx;
            }
        }
    }
}

// ---------------------------------------------------------------------------
extern "C" void kernel_launch(void* const* d_in, const int* in_sizes, int n_in,
                              void* d_out, int out_size, void* d_ws, size_t ws_size,
                              hipStream_t stream)
{
    const float* X   = (const float*)d_in[0];
    const float* Tsc = (const float*)d_in[1];
    const float* W10 = (const float*)d_in[2];  const float* b10 = (const float*)d_in[3];
    const float* W11 = (const float*)d_in[4];  const float* b11 = (const float*)d_in[5];
    const float* W12 = (const float*)d_in[6];  const float* b12 = (const float*)d_in[7];
    const float* W13 = (const float*)d_in[8];  const float* b13 = (const float*)d_in[9];
    const float* W20 = (const float*)d_in[10]; const float* b20 = (const float*)d_in[11];
    const float* W21 = (const float*)d_in[12]; const float* b21 = (const float*)d_in[13];
    const float* W22 = (const float*)d_in[14]; const float* b22 = (const float*)d_in[15];
    const float* Wf  = (const float*)d_in[16];

    float* ws  = (float*)d_ws;
    float* out = (float*)d_out;

    float2* TCS = (float2*)(ws + OF_TCS);
    float2* TP2 = (float2*)(ws + OF_TP2);
    float* CSUM = ws + OF_CSUM; float* SSUM = ws + OF_SSUM;
    float* HSUM = ws + OF_HSUM; float* RACC = ws + OF_RACC;
    float* M0 = ws + OF_M0; float* M1 = ws + OF_M1; float* M2 = ws + OF_M2;
    float* H1A = ws + OF_H1A; float* H1B = ws + OF_H1B;

    k1_tables<<<1, 1024, 0, stream>>>(X, TCS, TP2, CSUM, SSUM, HSUM);
    k2_pairs<<<NP, 256, 0, stream>>>(W20, b20, W21, b21, W22, b22,
                                     TCS, TP2, RACC, M0, M1, M2);
    l0_kernel<<<32, 256, 0, stream>>>(Tsc, W10, b10, TCS, CSUM, SSUM, RACC,
                                      H1A, HSUM + 0*64);
    lx_kernel<1><<<32, 256, 0, stream>>>(W11, b11, H1A, H1B, HSUM + 0*64, HSUM + 1*64,
                                         M0, (const float*)nullptr, (const float*)nullptr,
                                         (float*)nullptr);
    lx_kernel<2><<<32, 256, 0, stream>>>(W12, b12, H1B, H1A, HSUM + 1*64, HSUM + 2*64,
                                         M1, (const float*)nullptr, (const float*)nullptr,
                                         (float*)nullptr);
    lx_kernel<3><<<32, 256, 0, stream>>>(W13, b13, H1A, H1B, HSUM + 2*64, (float*)nullptr,
                                         M2, Wf, X, out);
}

// Round 4
// 524.897 us; speedup vs baseline: 9.7418x; 1.3909x over previous
//
#include <hip/hip_runtime.h>
#include <math.h>

// FermiNet-like forward, N=1024, DIM=3, all fp32.
//
// v4: kill the residual spill for real. v3 evidence: VGPR_Count=128 exactly
// (allocator's 16-waves/CU heuristic under launch_bounds(256,2)) with ~120
// floats peak-live (incl. compiler-hoisted 54-float sJ row) -> ~19 regs
// spilled/iter -> 161 MB scratch WRITE + L2 thrash -> 502 MB FETCH.
// Changes:
//   * k2: __launch_bounds__(256,1) -> VGPR cap ~512, allocator takes what it
//     needs (expect 160-224), zero spill.
//   * Trig tables row-major TROW[i][56]: (c,s) pairs for kd=0..23 then
//     (cp,sp) d=0..2. Per-thread float4 row reads (broadcast across the 8
//     q-lanes; 8 distinct rows/wave), full cache-line utilization through L1.
//   * l0 reads TROW too; TCS/TP2 layouts deleted.
// Unchanged (validated v3, absmax 1.9e-6, 0 bank conflicts): XOR-swizzled sH
// h-exchange, barrier-free main loop, wave reductions, lx kernels.

#define NP 1024

// ---- workspace offsets (in floats) ----
static const size_t OF_TROW = 0;                    // NP*56 row-major trig
static const size_t OF_CSUM = OF_TROW + NP*56;      // 24  sum_i cos
static const size_t OF_SSUM = OF_CSUM + 24;         // 24  sum_i sin
static const size_t OF_HSUM = OF_SSUM + 24;         // 3*64  h1 row-sum per layer
static const size_t OF_RACC = OF_HSUM + 192;        // 1024  sum_i r(i,j)
static const size_t OF_M0   = OF_RACC + NP;         // 1024*32 sum_i h2 stage0
static const size_t OF_M1   = OF_M0 + NP*32;        // 1024*32 stage1
static const size_t OF_M2   = OF_M1 + NP*32;        // 1024*32 stage2
static const size_t OF_H1A  = OF_M2 + NP*32;        // 1024*64
static const size_t OF_H1B  = OF_H1A + NP*64;       // 1024*64
// end: OF_H1B + NP*64 = 287984 floats (~1.15 MB)

__device__ __forceinline__ float ftanh(float x) {
    float e = __expf(2.0f * x);
    return 1.0f - __fdividef(2.0f, e + 1.0f);
}

// ---------------------------------------------------------------------------
// K1: per-particle trig rows (TROW[i][56]) + column sums + zero HSUM.
// ---------------------------------------------------------------------------
__global__ __launch_bounds__(1024) void k1_tables(
    const float* __restrict__ X,
    float* __restrict__ TROW,
    float* __restrict__ CSUM, float* __restrict__ SSUM,
    float* __restrict__ HSUM)
{
    const int i = threadIdx.x;
    float ck[24], sk[24], cp[3], sp[3];
#pragma unroll
    for (int d = 0; d < 3; ++d) {
        float x = X[i*3 + d];
        sincospif(x, &sp[d], &cp[d]);
#pragma unroll
        for (int k = 0; k < 8; ++k) {
            float s, c;
            sincospif(2.0f*(float)(k+1)*x, &s, &c);
            ck[k*3 + d] = c;  sk[k*3 + d] = s;
        }
    }
    float4* row = (float4*)(TROW + (size_t)i*56);
#pragma unroll
    for (int t = 0; t < 12; ++t)
        row[t] = make_float4(ck[2*t], sk[2*t], ck[2*t+1], sk[2*t+1]);
    row[12] = make_float4(cp[0], sp[0], cp[1], sp[1]);
    row[13] = make_float4(cp[2], sp[2], 0.f, 0.f);

    __shared__ float part[48*16];
    const int lane = i & 63, wv = i >> 6;
#pragma unroll
    for (int v = 0; v < 24; ++v) {
        float a = ck[v], b = sk[v];
#pragma unroll
        for (int off = 32; off; off >>= 1) {
            a += __shfl_down(a, off, 64);
            b += __shfl_down(b, off, 64);
        }
        if (lane == 0) { part[v*16 + wv] = a; part[(24+v)*16 + wv] = b; }
    }
    __syncthreads();
    if (i < 48) {
        float s = 0.f;
#pragma unroll
        for (int w = 0; w < 16; ++w) s += part[i*16 + w];
        if (i < 24) CSUM[i] = s; else SSUM[i-24] = s;
    }
    if (i < 192) HSUM[i] = 0.0f;
}

// ---------------------------------------------------------------------------
// K2: pair kernel. Block = column j. q = tid&7 (cols q*4..q*4+3), g = tid>>3.
// i = it*128 + m*32 + g, m=0..3, it=0..7. No barriers in the main loop.
// ---------------------------------------------------------------------------
__global__ __launch_bounds__(256, 1) void k2_pairs(
    const float* __restrict__ W20, const float* __restrict__ b20,
    const float* __restrict__ W21, const float* __restrict__ b21,
    const float* __restrict__ W22, const float* __restrict__ b22,
    const float* __restrict__ TROW,
    float* __restrict__ RACC, float* __restrict__ M0,
    float* __restrict__ M1, float* __restrict__ M2)
{
    __shared__ __align__(16) float sW0[49*32];
    __shared__ __align__(16) float sW1[32*32];
    __shared__ __align__(16) float sW2[32*32];
    __shared__ __align__(16) float sH[4*32*32];   // float4 slots, XOR-swizzled
    __shared__ float sB[96];
    __shared__ __align__(16) float sJ[56];        // row j of TROW
    __shared__ float sPart[4][97];

    const int tid = threadIdx.x;
    const int j = blockIdx.x;
    const int q = tid & 7;
    const int g = tid >> 3;
    const int c0 = q * 4;
    const int gx = g & 7;

    for (int v = tid; v < 49*32; v += 256) sW0[v] = W20[v];
    for (int v = tid; v < 32*32; v += 256) sW1[v] = W21[v];
    for (int v = tid; v < 32*32; v += 256) sW2[v] = W22[v];
    if (tid < 32) { sB[tid] = b20[tid]; sB[32+tid] = b21[tid]; sB[64+tid] = b22[tid]; }
    if (tid < 14) ((float4*)sJ)[tid] = ((const float4*)(TROW + (size_t)j*56))[tid];
    __syncthreads();

    float4* sH4 = (float4*)sH;        // index: (m*32+g)*8 + (slot ^ gx)

    float a0[4], a1[4], a2[4];
#pragma unroll
    for (int u = 0; u < 4; ++u) { a0[u] = 0.f; a1[u] = 0.f; a2[u] = 0.f; }
    float racc = 0.f;

#pragma unroll 1
    for (int it = 0; it < 8; ++it) {
        const int ib = it*128 + g;            // + m*32 -> i
        const float4* row0 = (const float4*)(TROW + (size_t)(ib +  0)*56);
        const float4* row1 = (const float4*)(TROW + (size_t)(ib + 32)*56);
        const float4* row2 = (const float4*)(TROW + (size_t)(ib + 64)*56);
        const float4* row3 = (const float4*)(TROW + (size_t)(ib + 96)*56);

        float z[4][4];
#pragma unroll
        for (int m = 0; m < 4; ++m) {
            z[m][0] = sB[c0+0]; z[m][1] = sB[c0+1];
            z[m][2] = sB[c0+2]; z[m][3] = sB[c0+3];
        }

        // ---- r feature (8x redundant across q-lanes) ----
        float rv[4];
#pragma unroll
        for (int m = 0; m < 4; ++m) {
            const float4* rw = (m==0)?row0:(m==1)?row1:(m==2)?row2:row3;
            float4 pa = rw[12], pb = rw[13];
            float sd0 = fmaf(pa.y, sJ[48], -(pa.x * sJ[49]));
            float sd1 = fmaf(pa.w, sJ[50], -(pa.z * sJ[51]));
            float sd2 = fmaf(pb.y, sJ[52], -(pb.x * sJ[53]));
            float r2 = fmaf(sd0, sd0, fmaf(sd1, sd1, sd2*sd2));
            rv[m] = sqrtf(r2);
            racc += rv[m];
        }
        {
            const float4 w = *(const float4*)(sW0 + c0);   // row 0
#pragma unroll
            for (int m = 0; m < 4; ++m) {
                z[m][0]=fmaf(rv[m],w.x,z[m][0]); z[m][1]=fmaf(rv[m],w.y,z[m][1]);
                z[m][2]=fmaf(rv[m],w.z,z[m][2]); z[m][3]=fmaf(rv[m],w.w,z[m][3]);
            }
        }
        // ---- 48 cos/sin features, 2 kd per float4 chunk ----
#pragma unroll
        for (int t = 0; t < 12; ++t) {
            float4 cs0 = row0[t], cs1 = row1[t], cs2 = row2[t], cs3 = row3[t];
#pragma unroll
            for (int sub = 0; sub < 2; ++sub) {
                const int kd = 2*t + sub;
                const int k = kd/3, d = kd - k*3;
                const float ckj = sJ[2*kd], skj = sJ[2*kd+1];
                const float4 wc  = *(const float4*)(sW0 + (1 + k*6 + d)*32 + c0);
                const float4 wsn = *(const float4*)(sW0 + (4 + k*6 + d)*32 + c0);
#pragma unroll
                for (int m = 0; m < 4; ++m) {
                    const float4 cs = (m==0)?cs0:(m==1)?cs1:(m==2)?cs2:cs3;
                    float ci = sub ? cs.z : cs.x;
                    float si = sub ? cs.w : cs.y;
                    float cc = fmaf(ci, ckj, si * skj);
                    float ss = fmaf(si, ckj, -(ci * skj));
                    z[m][0] = fmaf(cc, wc.x, fmaf(ss, wsn.x, z[m][0]));
                    z[m][1] = fmaf(cc, wc.y, fmaf(ss, wsn.y, z[m][1]));
                    z[m][2] = fmaf(cc, wc.z, fmaf(ss, wsn.z, z[m][2]));
                    z[m][3] = fmaf(cc, wc.w, fmaf(ss, wsn.w, z[m][3]));
                }
            }
        }

        // ---- layer 0 tanh; publish h0 to sH ----
        float h0own[4][4];
#pragma unroll
        for (int m = 0; m < 4; ++m) {
            float4 hv;
            hv.x = ftanh(z[m][0]); hv.y = ftanh(z[m][1]);
            hv.z = ftanh(z[m][2]); hv.w = ftanh(z[m][3]);
            h0own[m][0]=hv.x; h0own[m][1]=hv.y; h0own[m][2]=hv.z; h0own[m][3]=hv.w;
            a0[0]+=hv.x; a0[1]+=hv.y; a0[2]+=hv.z; a0[3]+=hv.w;
            sH4[(m*32+g)*8 + (q ^ gx)] = hv;
            z[m][0]=sB[32+c0+0]; z[m][1]=sB[32+c0+1];
            z[m][2]=sB[32+c0+2]; z[m][3]=sB[32+c0+3];
        }

        // ---- layer 1 matvec (reads sH written by own wave-group) ----
#pragma unroll
        for (int kc = 0; kc < 8; ++kc) {
            const float4 w0 = *(const float4*)(sW1 + (kc*4+0)*32 + c0);
            const float4 w1 = *(const float4*)(sW1 + (kc*4+1)*32 + c0);
            const float4 w2 = *(const float4*)(sW1 + (kc*4+2)*32 + c0);
            const float4 w3 = *(const float4*)(sW1 + (kc*4+3)*32 + c0);
#pragma unroll
            for (int m = 0; m < 4; ++m) {
                const float4 hc = sH4[(m*32+g)*8 + (kc ^ gx)];
                z[m][0]=fmaf(hc.x,w0.x,fmaf(hc.y,w1.x,fmaf(hc.z,w2.x,fmaf(hc.w,w3.x,z[m][0]))));
                z[m][1]=fmaf(hc.x,w0.y,fmaf(hc.y,w1.y,fmaf(hc.z,w2.y,fmaf(hc.w,w3.y,z[m][1]))));
                z[m][2]=fmaf(hc.x,w0.z,fmaf(hc.y,w1.z,fmaf(hc.z,w2.z,fmaf(hc.w,w3.z,z[m][2]))));
                z[m][3]=fmaf(hc.x,w0.w,fmaf(hc.y,w1.w,fmaf(hc.z,w2.w,fmaf(hc.w,w3.w,z[m][3]))));
            }
        }
        float h1own[4][4];
#pragma unroll
        for (int m = 0; m < 4; ++m) {
            float4 hv;
            hv.x = ftanh(z[m][0]) + h0own[m][0];
            hv.y = ftanh(z[m][1]) + h0own[m][1];
            hv.z = ftanh(z[m][2]) + h0own[m][2];
            hv.w = ftanh(z[m][3]) + h0own[m][3];
            h1own[m][0]=hv.x; h1own[m][1]=hv.y; h1own[m][2]=hv.z; h1own[m][3]=hv.w;
            a1[0]+=hv.x; a1[1]+=hv.y; a1[2]+=hv.z; a1[3]+=hv.w;
            sH4[(m*32+g)*8 + (q ^ gx)] = hv;       // overwrite h0 (reads done)
            z[m][0]=sB[64+c0+0]; z[m][1]=sB[64+c0+1];
            z[m][2]=sB[64+c0+2]; z[m][3]=sB[64+c0+3];
        }

        // ---- layer 2 matvec ----
#pragma unroll
        for (int kc = 0; kc < 8; ++kc) {
            const float4 w0 = *(const float4*)(sW2 + (kc*4+0)*32 + c0);
            const float4 w1 = *(const float4*)(sW2 + (kc*4+1)*32 + c0);
            const float4 w2 = *(const float4*)(sW2 + (kc*4+2)*32 + c0);
            const float4 w3 = *(const float4*)(sW2 + (kc*4+3)*32 + c0);
#pragma unroll
            for (int m = 0; m < 4; ++m) {
                const float4 hc = sH4[(m*32+g)*8 + (kc ^ gx)];
                z[m][0]=fmaf(hc.x,w0.x,fmaf(hc.y,w1.x,fmaf(hc.z,w2.x,fmaf(hc.w,w3.x,z[m][0]))));
                z[m][1]=fmaf(hc.x,w0.y,fmaf(hc.y,w1.y,fmaf(hc.z,w2.y,fmaf(hc.w,w3.y,z[m][1]))));
                z[m][2]=fmaf(hc.x,w0.z,fmaf(hc.y,w1.z,fmaf(hc.z,w2.z,fmaf(hc.w,w3.z,z[m][2]))));
                z[m][3]=fmaf(hc.x,w0.w,fmaf(hc.y,w1.w,fmaf(hc.z,w2.w,fmaf(hc.w,w3.w,z[m][3]))));
            }
        }
#pragma unroll
        for (int m = 0; m < 4; ++m) {
            a2[0] += ftanh(z[m][0]) + h1own[m][0];
            a2[1] += ftanh(z[m][1]) + h1own[m][1];
            a2[2] += ftanh(z[m][2]) + h1own[m][2];
            a2[3] += ftanh(z[m][3]) + h1own[m][3];
        }
    }

    // ---- reduction: over g within wave, then across 4 waves via LDS ----
    const int lane = tid & 63, wid = tid >> 6;
#pragma unroll
    for (int u = 0; u < 4; ++u) {
#pragma unroll
        for (int mask = 8; mask < 64; mask <<= 1) {
            a0[u] += __shfl_xor(a0[u], mask, 64);
            a1[u] += __shfl_xor(a1[u], mask, 64);
            a2[u] += __shfl_xor(a2[u], mask, 64);
        }
    }
#pragma unroll
    for (int mask = 1; mask < 64; mask <<= 1) racc += __shfl_xor(racc, mask, 64);

    if (lane < 8) {
#pragma unroll
        for (int u = 0; u < 4; ++u) {
            sPart[wid][1  + lane*4 + u] = a0[u];
            sPart[wid][33 + lane*4 + u] = a1[u];
            sPart[wid][65 + lane*4 + u] = a2[u];
        }
    }
    if (lane == 0) sPart[wid][0] = racc;
    __syncthreads();
    if (tid < 97) {
        float s = sPart[0][tid] + sPart[1][tid] + sPart[2][tid] + sPart[3][tid];
        if (tid == 0)      RACC[j] = s * 0.125f;     // r computed 8x redundantly
        else if (tid < 33) M0[j*32 + (tid-1)]  = s;
        else if (tid < 65) M1[j*32 + (tid-33)] = s;
        else               M2[j*32 + (tid-65)] = s;
    }
}

// ---------------------------------------------------------------------------
// Phase B: h1 path. Thread = (row j, 8-channel chunk q). 8192 threads.
// ---------------------------------------------------------------------------
#define FMA8(fv, wptr) do { \
    const float4* w4_ = (const float4*)(wptr); \
    float4 a_ = w4_[0], b_ = w4_[1]; \
    z[0]=fmaf((fv),a_.x,z[0]); z[1]=fmaf((fv),a_.y,z[1]); \
    z[2]=fmaf((fv),a_.z,z[2]); z[3]=fmaf((fv),a_.w,z[3]); \
    z[4]=fmaf((fv),b_.x,z[4]); z[5]=fmaf((fv),b_.y,z[5]); \
    z[6]=fmaf((fv),b_.z,z[6]); z[7]=fmaf((fv),b_.w,z[7]); \
} while (0)

__device__ __forceinline__ void hsum_atomic(float* HS, const float h[8],
                                            int tid, int c0) {
    float hs[8];
#pragma unroll
    for (int u = 0; u < 8; ++u) {
        hs[u] = h[u];
#pragma unroll
        for (int mask = 8; mask < 64; mask <<= 1)
            hs[u] += __shfl_xor(hs[u], mask, 64);
    }
    if (((tid & 63) >> 3) == 0) {
#pragma unroll
        for (int u = 0; u < 8; ++u) atomicAdd(&HS[c0 + u], hs[u]);
    }
}

__global__ __launch_bounds__(256) void l0_kernel(
    const float* __restrict__ Tsc, const float* __restrict__ W10,
    const float* __restrict__ b10,
    const float* __restrict__ TROW,
    const float* __restrict__ CSUM, const float* __restrict__ SSUM,
    const float* __restrict__ RACC,
    float* __restrict__ H1A, float* __restrict__ HSUM0)
{
    const int tid = threadIdx.x;
    const int gid = blockIdx.x*256 + tid;
    const int j = gid >> 3, qq = gid & 7, c0 = qq*8;
    const float inv_n = 1.0f/1024.0f;
    const float t = Tsc[0];

    float z[8];
#pragma unroll
    for (int u = 0; u < 8; ++u) z[u] = b10[c0+u];

    FMA8(t, W10 + 0*64 + c0);
    FMA8(t, W10 + 17*64 + c0);
#pragma unroll
    for (int k = 0; k < 8; ++k) {
        float s, c; sincospif(2.0f*(float)(k+1)*t, &s, &c);
        FMA8(c, W10 + (1+2*k)*64 + c0);
        FMA8(c, W10 + (18+2*k)*64 + c0);
        FMA8(s, W10 + (2+2*k)*64 + c0);
        FMA8(s, W10 + (19+2*k)*64 + c0);
    }
    {
        float rb = RACC[j] * inv_n;
        FMA8(rb, W10 + 34*64 + c0);
    }
    const float4* rj = (const float4*)(TROW + (size_t)j*56);
#pragma unroll
    for (int tt = 0; tt < 12; ++tt) {
        float4 v = rj[tt];
#pragma unroll
        for (int sub = 0; sub < 2; ++sub) {
            const int kd = 2*tt + sub;
            float cj = sub ? v.z : v.x;
            float sj = sub ? v.w : v.y;
            float Cb = CSUM[kd]*inv_n, Sb = SSUM[kd]*inv_n;
            float cm = fmaf(cj, Cb, sj*Sb);
            float sm = fmaf(Sb, cj, -(Cb*sj));
            int k = kd/3, d = kd - k*3;
            FMA8(cm, W10 + (35 + k*6 + d)*64 + c0);
            FMA8(sm, W10 + (38 + k*6 + d)*64 + c0);
        }
    }
    float h[8];
#pragma unroll
    for (int u = 0; u < 8; ++u) {
        h[u] = ftanh(z[u]);                  // layer 0: no residual
        H1A[j*64 + c0 + u] = h[u];
    }
    hsum_atomic(HSUM0, h, tid, c0);
}

template<int LAYER>
__global__ __launch_bounds__(256) void lx_kernel(
    const float* __restrict__ W, const float* __restrict__ b,
    const float* __restrict__ hin, float* __restrict__ hout,
    const float* __restrict__ HSin, float* __restrict__ HSout,
    const float* __restrict__ M,
    const float* __restrict__ Wf, const float* __restrict__ X,
    float* __restrict__ out)
{
    const int tid = threadIdx.x;
    const int gid = blockIdx.x*256 + tid;
    const int j = gid >> 3, qq = gid & 7, c0 = qq*8;
    const float inv_n = 1.0f/1024.0f;

    float z[8];
#pragma unroll
    for (int u = 0; u < 8; ++u) z[u] = b[c0+u];
    const float* hrow = hin + j*64;
#pragma unroll 4
    for (int p = 0; p < 64; ++p) {
        float fv = hrow[p];
        FMA8(fv, W + p*64 + c0);
    }
#pragma unroll 4
    for (int p = 0; p < 64; ++p) {
        float fv = HSin[p] * inv_n;
        FMA8(fv, W + (64+p)*64 + c0);
    }
    const float* mrow = M + j*32;
#pragma unroll 4
    for (int p = 0; p < 32; ++p) {
        float fv = mrow[p] * inv_n;
        FMA8(fv, W + (128+p)*64 + c0);
    }
    float h[8];
#pragma unroll
    for (int u = 0; u < 8; ++u) h[u] = ftanh(z[u]) + hrow[c0+u];  // residual

    if (LAYER < 3) {
#pragma unroll
        for (int u = 0; u < 8; ++u) hout[j*64 + c0 + u] = h[u];
        hsum_atomic(HSout, h, tid, c0);
    } else {
        __shared__ float red[256][3];
        float p0 = 0.f, p1 = 0.f, p2 = 0.f;
#pragma unroll
        for (int u = 0; u < 8; ++u) {
            float hv = h[u];
            const float* wf = Wf + (c0+u)*3;
            p0 = fmaf(hv, wf[0], p0);
            p1 = fmaf(hv, wf[1], p1);
            p2 = fmaf(hv, wf[2], p2);
        }
        red[tid][0] = p0; red[tid][1] = p1; red[tid][2] = p2;
        __syncthreads();
        if (qq == 0) {
            float s0 = 0.f, s1 = 0.f, s2 = 0.f;
#pragma unroll
            for (int r = 0; r < 8; ++r) {
                s0 += red[tid+r][0]; s1 += red[tid+r][1]; s2 += red[tid+r][2];
            }
#pragma unroll
            for (int d = 0; d < 3; ++d) {
                float fx = 2.0f * X[j*3 + d];
                fx = fminf(fmaxf(fx, -10.0f), 10.0f);
                float s = (d == 0 ? s0 : (d == 1 ? s1 : s2));
                out[j*3 + d] = -s * fx;
            }
        }
    }
}

// ---------------------------------------------------------------------------
extern "C" void kernel_launch(void* const* d_in, const int* in_sizes, int n_in,
                              void* d_out, int out_size, void* d_ws, size_t ws_size,
                              hipStream_t stream)
{
    const float* X   = (const float*)d_in[0];
    const float* Tsc = (const float*)d_in[1];
    const float* W10 = (const float*)d_in[2];  const float* b10 = (const float*)d_in[3];
    const float* W11 = (const float*)d_in[4];  const float* b11 = (const float*)d_in[5];
    const float* W12 = (const float*)d_in[6];  const float* b12 = (const float*)d_in[7];
    const float* W13 = (const float*)d_in[8];  const float* b13 = (const float*)d_in[9];
    const float* W20 = (const float*)d_in[10]; const float* b20 = (const float*)d_in[11];
    const float* W21 = (const float*)d_in[12]; const float* b21 = (const float*)d_in[13];
    const float* W22 = (const float*)d_in[14]; const float* b22 = (const float*)d_in[15];
    const float* Wf  = (const float*)d_in[16];

    float* ws  = (float*)d_ws;
    float* out = (float*)d_out;

    float* TROW = ws + OF_TROW;
    float* CSUM = ws + OF_CSUM; float* SSUM = ws + OF_SSUM;
    float* HSUM = ws + OF_HSUM; float* RACC = ws + OF_RACC;
    float* M0 = ws + OF_M0; float* M1 = ws + OF_M1; float* M2 = ws + OF_M2;
    float* H1A = ws + OF_H1A; float* H1B = ws + OF_H1B;

    k1_tables<<<1, 1024, 0, stream>>>(X, TROW, CSUM, SSUM, HSUM);
    k2_pairs<<<NP, 256, 0, stream>>>(W20, b20, W21, b21, W22, b22,
                                     TROW, RACC, M0, M1, M2);
    l0_kernel<<<32, 256, 0, stream>>>(Tsc, W10, b10, TROW, CSUM, SSUM, RACC,
                                      H1A, HSUM + 0*64);
    lx_kernel<1><<<32, 256, 0, stream>>>(W11, b11, H1A, H1B, HSUM + 0*64, HSUM + 1*64,
                                         M0, (const float*)nullptr, (const float*)nullptr,
                                         (float*)nullptr);
    lx_kernel<2><<<32, 256, 0, stream>>>(W12, b12, H1B, H1A, HSUM + 1*64, HSUM + 2*64,
                                         M1, (const float*)nullptr, (const float*)nullptr,
                                         (float*)nullptr);
    lx_kernel<3><<<32, 256, 0, stream>>>(W13, b13, H1A, H1B, HSUM + 2*64, (float*)nullptr,
                                         M2, Wf, X, out);
}